// Round 4
// baseline (11271.366 us; speedup 1.0000x reference)
//
#include <hip/hip_runtime.h>
#include <math.h>

typedef unsigned short u16;
typedef unsigned int   u32;
typedef unsigned long long u64;
typedef __attribute__((ext_vector_type(8))) short short8;
typedef __attribute__((ext_vector_type(4))) float f32x4;
typedef __attribute__((ext_vector_type(4))) unsigned int u32x4;

__device__ __forceinline__ u16 f2bf(float f) {
    u32 u = __float_as_uint(f);
    u32 r = (u + 0x7fffu + ((u >> 16) & 1u)) >> 16;
    return (u16)r;
}
__device__ __forceinline__ u32 pk2(float a, float b) {
    return ((u32)f2bf(a)) | (((u32)f2bf(b)) << 16);
}
__device__ __forceinline__ float sigm(float x) { return 1.f / (1.f + __expf(-x)); }
__device__ __forceinline__ f32x4 mfma16(short8 a, short8 b, f32x4 c) {
    return __builtin_amdgcn_mfma_f32_16x16x32_bf16(a, b, c, 0, 0, 0);
}
__device__ __forceinline__ short8 ld8bf(const float* p) {
    short8 r;
#pragma unroll
    for (int j = 0; j < 8; ++j) r[j] = (short)f2bf(p[j]);
    return r;
}
// 16B cache-bypassing load/store straight at the coherence point.
__device__ __forceinline__ u32x4 ldg16cv4(const u16* p) {
    u32x4 r;
    asm volatile("global_load_dwordx4 %0, %1, off sc0 sc1" : "=v"(r) : "v"(p));
    return r;
}
__device__ __forceinline__ void stg16cv(u16* p, u32x4 v) {
    asm volatile("global_store_dwordx4 %0, %1, off sc0 sc1" :: "v"(p), "v"(v) : "memory");
}
__device__ __forceinline__ void waitvm() {
    asm volatile("s_waitcnt vmcnt(0)" ::: "memory");
}
// NOT-decode a published chunk into LDS (16B aligned).
__device__ __forceinline__ void st_not16(u16* dst, u32x4 w) {
    u32x4 d; d[0] = ~w[0]; d[1] = ~w[1]; d[2] = ~w[2]; d[3] = ~w[3];
    *(u32x4*)dst = d;
}
__device__ __forceinline__ void st_zero16(u16* dst) {
    u32x4 d = {0u, 0u, 0u, 0u};
    *(u32x4*)dst = d;
}

#define FLAG_STRIDE 16   /* ints -> 64B per flag slot */
#define XL_OFF 16384000
#define PS_OFF 16384016

// ws layout (bytes)
#define WS_FLAGS   0        /* progress counters, 32768 B */
#define WS_HBUF_F  32768    /* 3 layers x 16 slots x 16KB = 786432 -> 819200 */
#define WS_HBUF_W  819200   /* 16 slots x 8KB = 131072 -> 950272 */
#define WS_REPS    950272   /* 1600x512 fp32 = 3276800 -> 4227072 */
#define WS_RW      4227072  /* 1600x256 bf16 = 819200 -> 5046272 */
#define WS_HSEQ    5046272  /* 1600x256 fp32 = 1638400 -> 6684672 */
#define WS_FPWB    6684672  /* 512x512 bf16 = 524288 -> 7208960 */

// ---------------------------------------------------------------------------
// Persistent 3-layer frame LSTM. 192 WGs (64/layer), 128 threads (round-0
// shape). h exchange is SELF-VALIDATING: producers publish ~pk (bitwise NOT
// of the packed bf16 pair); 0 == "not written" (pk==0xFFFFFFFF would need
// bf16 -NaN, impossible for |h|<=1). Consumers poll the data chunks directly
// with s_sleep backoff and partial re-load: detection DELIVERS the payload,
// removing the store-ack and the flag hop from the recurrence critical path.
// Ring-16; producers re-arm (zero) slot (t+8)&15 each step. Within-layer
// publish skew <=1 by construction (each step polls all peers' previous h),
// so only CROSS-layer over-run needs gating: lazy next-layer progress flags,
// checked against a cached copy and reloaded only when stale.
// ---------------------------------------------------------------------------
template<int KTIN, bool L0, bool HASNEXT>
__device__ __forceinline__ void frame_body(
    const int layer, const int kwg,
    const float* __restrict__ Wih, const float* __restrict__ Whh, const float* __restrict__ bias,
    const float* __restrict__ x, u16* __restrict__ hbuf, int* __restrict__ flags,
    float* __restrict__ h3out, float* sC, u16* sxpad, u16* AsIn, u16* AsOwn)
{
    const int tid  = threadIdx.x;
    const int lane = tid & 63;
    const int wave = tid >> 6;
    const int n16  = lane & 15;
    const int quad = lane >> 4;
    const int koff = quad * 8;

    if (L0) {                                            // zero the x pad cols [80,96)
        for (int e = tid; e < 256; e += 128) sxpad[(e >> 4) * 96 + 80 + (e & 15)] = 0;
    }

    // B fragments in registers. wave0 -> tile (i|f), wave1 -> tile (g|o).
    const int grow = wave * 1024 + ((n16 >> 3) * 512) + kwg * 8 + (n16 & 7);
    short8 bfr[KTIN + 16];
#pragma unroll
    for (int kt = 0; kt < KTIN; ++kt) {
        short8 v = {0,0,0,0,0,0,0,0};
        const int k = kt * 32 + koff;
        if (L0) { if (k + 8 <= 80) v = ld8bf(Wih + grow * 80 + k); }
        else    { v = ld8bf(Wih + (size_t)grow * 512 + k); }
        bfr[kt] = v;
    }
#pragma unroll
    for (int kt = 0; kt < 16; ++kt)
        bfr[KTIN + kt] = ld8bf(Whh + (size_t)grow * 512 + kt * 32 + koff);

    // gate phase: one (batch, col) value per thread; c-state in a register
    const int gb = tid & 15;        // batch
    const int gj = tid >> 4;        // col within WG, 0..7
    const int gc = kwg * 8 + gj;    // global h col
    const float bI = bias[gc], bF = bias[512 + gc], bG = bias[1024 + gc], bO = bias[1536 + gc];
    float creg = 0.f;

    int* myflag   = flags + (layer * 64 + kwg) * FLAG_STRIDE;
    const int* fN = flags + ((layer + 1) * 64) * FLAG_STRIDE;
    int fnc = 0;                                     // cached next-layer progress (wave0 lanes)
    u16* lbase = hbuf + (size_t)layer * 16 * 8192;
    const u16* pbase = hbuf + (size_t)(layer > 0 ? layer - 1 : 0) * 16 * 8192;
    __syncthreads();

    for (int t = 0; t < 2000; ++t) {
        // ---- wave0: (lazily gated) re-arm slot (t+8)&15 with zeros ----
        if (wave == 0) {
            if (HASNEXT && !__all(fnc >= t - 6)) {
                int g2 = 0;
                do {
                    fnc = __hip_atomic_load(fN + lane * FLAG_STRIDE, __ATOMIC_RELAXED, __HIP_MEMORY_SCOPE_AGENT);
                    if (__all(fnc >= t - 6)) break;
                    __builtin_amdgcn_s_sleep(2);
                } while (++g2 < (1 << 22));
            }
            if (lane < 16) {                     // 16 rows x this WG's 8 cols (16B)
                u32x4 zz = {0u, 0u, 0u, 0u};
                stg16cv(lbase + ((size_t)((t + 8) & 15)) * 8192 + lane * 512 + kwg * 8, zz);
            }
        }

        // ---- issue x loads early (L0) so they fly under the poll ----
        float4 xv0, xv1, xv2;
        const int e0 = tid, e1 = tid + 128, e2 = tid + 256;
        if (L0) {
            xv0 = *(const float4*)(x + ((size_t)(e0 / 20) * 2000 + t) * 80 + (e0 % 20) * 4);
            xv1 = *(const float4*)(x + ((size_t)(e1 / 20) * 2000 + t) * 80 + (e1 % 20) * 4);
            if (e2 < 320)
                xv2 = *(const float4*)(x + ((size_t)(e2 / 20) * 2000 + t) * 80 + (e2 % 20) * 4);
        }

        // ---- data-poll: chunks [0..7]=hin (prev layer h_t), [8..15]=own h_{t-1} ----
        u32x4 v[16];
        const u16* hin  = pbase + ((size_t)(t & 15)) * 8192;
        const u16* hown = lbase + ((size_t)((t - 1) & 15)) * 8192;
        u32 pend = (L0 ? 0u : 0x00FFu) | (t > 0 ? 0xFF00u : 0u);
        int rounds = 0;
        while (pend) {
#pragma unroll
            for (int i = 0; i < 8; ++i)
                if (!L0 && (pend & (1u << i)))   v[i]     = ldg16cv4(hin  + (tid + 128 * i) * 8);
#pragma unroll
            for (int i = 0; i < 8; ++i)
                if (pend & (0x100u << i))        v[8 + i] = ldg16cv4(hown + (tid + 128 * i) * 8);
            waitvm();
#pragma unroll
            for (int i = 0; i < 16; ++i)
                if ((pend & (1u << i)) && v[i][0] && v[i][1] && v[i][2] && v[i][3])
                    pend &= ~(1u << i);
            if (pend) __builtin_amdgcn_s_sleep(2);   // backoff only on miss
            if (++rounds > (1 << 20)) break;         // anti-hang escape
        }

        // ---- stage into LDS (NOT-decode) ----
        if (L0) {
            u32* d0 = (u32*)(sxpad + (e0 / 20) * 96 + (e0 % 20) * 4);
            d0[0] = pk2(xv0.x, xv0.y); d0[1] = pk2(xv0.z, xv0.w);
            u32* d1 = (u32*)(sxpad + (e1 / 20) * 96 + (e1 % 20) * 4);
            d1[0] = pk2(xv1.x, xv1.y); d1[1] = pk2(xv1.z, xv1.w);
            if (e2 < 320) {
                u32* d2 = (u32*)(sxpad + (e2 / 20) * 96 + (e2 % 20) * 4);
                d2[0] = pk2(xv2.x, xv2.y); d2[1] = pk2(xv2.z, xv2.w);
            }
        }
#pragma unroll
        for (int i = 0; i < 8; ++i) {
            const int c = tid + 128 * i;
            const int row = c >> 6, col8 = (c & 63) << 3;
            if (!L0) st_not16(AsIn + row * 520 + col8, v[i]);
            if (t > 0) st_not16(AsOwn + row * 520 + col8, v[8 + i]);
            else       st_zero16(AsOwn + row * 520 + col8);
        }
        __syncthreads();

        // ---- gate GEMM ----
        f32x4 acc[4] = {{0,0,0,0},{0,0,0,0},{0,0,0,0},{0,0,0,0}};
#pragma unroll
        for (int kt = 0; kt < KTIN; ++kt) {
            short8 a;
            if (L0) a = *(const short8*)(sxpad + n16 * 96 + kt * 32 + koff);
            else    a = *(const short8*)(AsIn + n16 * 520 + kt * 32 + koff);
            acc[kt & 3] = mfma16(a, bfr[kt], acc[kt & 3]);
        }
#pragma unroll
        for (int kt = 0; kt < 16; ++kt) {
            short8 a = *(const short8*)(AsOwn + n16 * 520 + kt * 32 + koff);
            acc[(KTIN + kt) & 3] = mfma16(a, bfr[KTIN + kt], acc[(KTIN + kt) & 3]);
        }
        const f32x4 C = acc[0] + acc[1] + acc[2] + acc[3];
#pragma unroll
        for (int r = 0; r < 4; ++r)
            sC[(wave * 16 + quad * 4 + r) * 17 + n16] = C[r];   // [wave*16+batch][gate]
        __syncthreads();

        // ---- gate math on all 128 lanes + self-validating publish ----
        const float gi = sC[gb * 17 + gj]            + bI;
        const float gf = sC[gb * 17 + 8 + gj]        + bF;
        const float gg = sC[(16 + gb) * 17 + gj]     + bG;
        const float go = sC[(16 + gb) * 17 + 8 + gj] + bO;
        const float cn = sigm(gf) * creg + sigm(gi) * tanhf(gg);
        const float hn = sigm(go) * tanhf(cn);
        creg = cn;
        const u32 mb = (u32)f2bf(hn);
        const u32 nb = (u32)__shfl_xor((int)mb, 16, 64);
        if (!(gj & 1)) {
            u32* hd = (u32*)(lbase + ((size_t)(t & 15)) * 8192) + gb * 256 + kwg * 4 + (gj >> 1);
            __hip_atomic_store(hd, ~(mb | (nb << 16)), __ATOMIC_RELAXED, __HIP_MEMORY_SCOPE_AGENT);
        }
        if (!HASNEXT)   // layer 2 output (fp32, off critical path)
            h3out[((size_t)(gb * 2000 + t)) * 512 + gc] = hn;
        if (tid == 0)   // progress counter (gates upstream re-arm only)
            __hip_atomic_store(myflag, t + 1, __ATOMIC_RELAXED, __HIP_MEMORY_SCOPE_AGENT);
    }
}

__global__ __launch_bounds__(128, 1) void k_frame_lstm(
    const float* __restrict__ x,
    const float* __restrict__ Wih0, const float* __restrict__ Whh0, const float* __restrict__ b0,
    const float* __restrict__ Wih1, const float* __restrict__ Whh1, const float* __restrict__ b1,
    const float* __restrict__ Wih2, const float* __restrict__ Whh2, const float* __restrict__ b2,
    u16* hbuf, int* flags, float* h3out)
{
    __shared__ __align__(16) u16 sxpad[16 * 96];
    __shared__ __align__(16) u16 AsIn[16 * 520];
    __shared__ __align__(16) u16 AsOwn[16 * 520];
    __shared__ float sC[32 * 17];
    const int wgid = blockIdx.x;
    const int layer = wgid >> 6;
    const int kwg = wgid & 63;
    if (layer == 0)      frame_body<3,  true,  true >(0, kwg, Wih0, Whh0, b0, x, hbuf, flags, h3out, sC, sxpad, AsIn, AsOwn);
    else if (layer == 1) frame_body<16, false, true >(1, kwg, Wih1, Whh1, b1, x, hbuf, flags, h3out, sC, sxpad, AsIn, AsOwn);
    else                 frame_body<16, false, false>(2, kwg, Wih2, Whh2, b2, x, hbuf, flags, h3out, sC, sxpad, AsIn, AsOwn);
}

// ---------------------------------------------------------------------------
// Persistent word LSTM: 8 WGs x 512 threads, 100 steps, H=256, K=256+256.
// Same self-validating data-poll (1 own chunk/thread, LDS-deduped);
// within-layer skew <=1 so ring-16 re-arm needs no gating; no flags at all.
// Re-arm: FULL coverage of this WG's 32 cols x 16 rows (64 lanes x 16B).
// ---------------------------------------------------------------------------
__global__ __launch_bounds__(512, 1) void k_word_lstm(
    const u16* __restrict__ rW, const float* __restrict__ Wih,
    const float* __restrict__ Whh, const float* __restrict__ bias,
    u16* __restrict__ hbufw, float* __restrict__ hseq)
{
    __shared__ __align__(16) u16 AsIn[16 * 264];
    __shared__ __align__(16) u16 AsOwn[16 * 264];
    __shared__ float sC[32 * 65];
    const int tid = threadIdx.x;
    const int lane = tid & 63;
    const int wave = tid >> 6;
    const int n16 = lane & 15;
    const int quad = lane >> 4;
    const int koff = quad * 8;
    const int gp = wave >> 2;
    const int cs = wave & 3;
    const int kwg = blockIdx.x;  // 0..7

    const int grow = gp * 512 + ((n16 >> 3) * 256) + kwg * 32 + cs * 8 + (n16 & 7);
    short8 bfr[16];
#pragma unroll
    for (int kt = 0; kt < 8; ++kt) bfr[kt]     = ld8bf(Wih + (size_t)grow * 256 + kt * 32 + koff);
#pragma unroll
    for (int kt = 0; kt < 8; ++kt) bfr[8 + kt] = ld8bf(Whh + (size_t)grow * 256 + kt * 32 + koff);
    const int gb = tid & 15;
    const int gj = tid >> 4;        // 0..31
    const int gc = kwg * 32 + gj;
    const float bI = bias[gc], bF = bias[256 + gc], bG = bias[512 + gc], bO = bias[768 + gc];
    float creg = 0.f;
    __syncthreads();

    for (int t = 0; t < 100; ++t) {
        // re-arm slot (t+8)&15: 16 rows x 32 cols (FULL coverage, 64 x 16B)
        if (wave == 0) {
            u32x4 zz = {0u, 0u, 0u, 0u};
            stg16cv(hbufw + ((size_t)((t + 8) & 15)) * 4096
                    + (lane >> 2) * 256 + kwg * 32 + (lane & 3) * 8, zz);
        }

        // data-poll own h_{t-1}: 1 chunk per thread
        const u16* hown = hbufw + ((size_t)((t - 1) & 15)) * 4096;
        const int b = tid >> 5, k8 = (tid & 31) << 3;
        const short8 rv = *(const short8*)(rW + ((size_t)(b * 100 + t)) * 256 + k8);  // cached
        u32x4 hv;
        if (t > 0) {
            int rounds = 0;
            bool ok = false;
            while (!ok) {
                hv = ldg16cv4(hown + b * 256 + k8);
                waitvm();
                ok = hv[0] && hv[1] && hv[2] && hv[3];
                if (!ok) __builtin_amdgcn_s_sleep(2);
                if (++rounds > (1 << 20)) break;
            }
        }
        if (t > 0) st_not16(AsOwn + b * 264 + k8, hv);
        else       st_zero16(AsOwn + b * 264 + k8);
        *(short8*)(AsIn + b * 264 + k8) = rv;
        __syncthreads();

        f32x4 acc[4] = {{0,0,0,0},{0,0,0,0},{0,0,0,0},{0,0,0,0}};
#pragma unroll
        for (int kt = 0; kt < 8; ++kt) {
            short8 a = *(const short8*)(AsIn + n16 * 264 + kt * 32 + koff);
            acc[kt & 3] = mfma16(a, bfr[kt], acc[kt & 3]);
        }
#pragma unroll
        for (int kt = 0; kt < 8; ++kt) {
            short8 a = *(const short8*)(AsOwn + n16 * 264 + kt * 32 + koff);
            acc[kt & 3] = mfma16(a, bfr[8 + kt], acc[kt & 3]);
        }
        const f32x4 C = acc[0] + acc[1] + acc[2] + acc[3];
#pragma unroll
        for (int r = 0; r < 4; ++r)
            sC[(gp * 16 + quad * 4 + r) * 65 + cs * 16 + n16] = C[r];
        __syncthreads();

        const int cs2 = gj >> 3, jl = gj & 7;
        const float gi = sC[gb * 65 + cs2 * 16 + jl]            + bI;
        const float gf = sC[gb * 65 + cs2 * 16 + 8 + jl]        + bF;
        const float gg = sC[(16 + gb) * 65 + cs2 * 16 + jl]     + bG;
        const float go = sC[(16 + gb) * 65 + cs2 * 16 + 8 + jl] + bO;
        const float cn = sigm(gf) * creg + sigm(gi) * tanhf(gg);
        const float hn = sigm(go) * tanhf(cn);
        creg = cn;
        const u32 mb = (u32)f2bf(hn);
        const u32 nb = (u32)__shfl_xor((int)mb, 16, 64);
        if (!(gj & 1)) {
            u32* hd = (u32*)(hbufw + ((size_t)(t & 15)) * 4096) + gb * 128 + kwg * 16 + (gj >> 1);
            __hip_atomic_store(hd, ~(mb | (nb << 16)), __ATOMIC_RELAXED, __HIP_MEMORY_SCOPE_AGENT);
        }
        hseq[((size_t)(gb * 100 + t)) * 256 + gc] = hn;
    }
}

// ---------------------------------------------------------------------------
// Ragged tail-mean pooling from fp32 h3 (in d_out): reps fp32 (ws)
// ---------------------------------------------------------------------------
__global__ void k_pool(const float* __restrict__ h3, const int* __restrict__ x_lens,
                       const int* __restrict__ wstarts, const int* __restrict__ wends,
                       const int* __restrict__ wlens, const int* __restrict__ tailp,
                       float* __restrict__ reps)
{
    const int rw = blockIdx.x;
    const int b = rw / 100, w = rw - b * 100;
    const int tid = threadIdx.x;
    const int xl = x_lens[b];
    const int we = wends[rw];
    const int s0 = wstarts[rw];
    const int wl = wlens[b];
    const int tail = tailp[0];
    int ef = we < xl ? we : xl;
    int sf = s0 > 0 ? s0 : 0;
    int i0 = ef - tail; if (i0 < sf) i0 = sf;
    const bool valid = (w < wl) && (we > 0) && (ef > sf) && (ef > i0);
    float a0 = 0.f, a1 = 0.f;
    if (valid) {
        for (int t = i0; t < ef; ++t) {
            const float* hp = h3 + ((size_t)(b * 2000 + t)) * 512;
            a0 += hp[tid];
            a1 += hp[tid + 256];
        }
        const float inv = 1.f / (float)(ef - i0);
        a0 *= inv; a1 *= inv;
    }
    reps[(size_t)rw * 512 + tid] = a0;
    reps[(size_t)rw * 512 + tid + 256] = a1;
}

// ---------------------------------------------------------------------------
// In-place frame projection: y[b,t,:] = mask(h3[b,t,:]) @ fpW^T + fpb (fp32)
// ---------------------------------------------------------------------------
__global__ __launch_bounds__(256, 2) void k_frame_proj(
    float* __restrict__ y, const int* __restrict__ x_lens,
    const u16* __restrict__ fpWb, const float* __restrict__ fpb)
{
    __shared__ __align__(16) u16 As[16 * 520];
    const int tid = threadIdx.x, lane = tid & 63, wave = tid >> 6;
    const int n16 = lane & 15, quad = lane >> 4, koff = quad * 8;
    const int blk = blockIdx.x;          // 2000 blocks: 125 per batch
    const int b = blk / 125;
    const int t0 = (blk - b * 125) * 16;
    const int xl = x_lens[b];
    for (int c = tid; c < 2048; c += 256) {      // 16 rows x 128 float4
        const int row = c >> 7;
        const int q = c & 127;
        const int t = t0 + row;
        float4 v = {0.f, 0.f, 0.f, 0.f};
        if (t < xl) v = *(const float4*)(y + ((size_t)(b * 2000 + t)) * 512 + q * 4);
        u32* d = (u32*)(As + row * 520 + q * 4);
        d[0] = pk2(v.x, v.y);
        d[1] = pk2(v.z, v.w);
    }
    __syncthreads();
    const size_t rowbase = (size_t)b * 2000 + t0;
    for (int ct = 0; ct < 8; ++ct) {
        const int col0 = (wave * 8 + ct) * 16;
        f32x4 acc = {0, 0, 0, 0};
#pragma unroll
        for (int kt = 0; kt < 16; ++kt) {
            short8 a = *(const short8*)(As + n16 * 520 + kt * 32 + koff);
            short8 wv = *(const short8*)(fpWb + ((size_t)(col0 + n16)) * 512 + kt * 32 + koff);
            acc = mfma16(a, wv, acc);
        }
        const float bn = fpb[col0 + n16];
#pragma unroll
        for (int r = 0; r < 4; ++r) {
            const int m = quad * 4 + r;
            y[(rowbase + m) * 512 + col0 + n16] = acc[r] + bn;
        }
    }
}

// ---------------------------------------------------------------------------
// word_proj: Linear(512->256) + LayerNorm + exact GELU per (b,w) row.
// ---------------------------------------------------------------------------
__global__ void k_word_proj(const float* __restrict__ reps, const float* __restrict__ wpW,
                            const float* __restrict__ wpb, const float* __restrict__ lnW,
                            const float* __restrict__ lnB, u16* __restrict__ rW)
{
    __shared__ float sx[512];
    __shared__ float red[512];
    const int tid = threadIdx.x;
    const int row = blockIdx.x;
    for (int k = tid; k < 512; k += 256) sx[k] = reps[(size_t)row * 512 + k];
    __syncthreads();
    float acc = wpb[tid];
    const float4* wr = (const float4*)(wpW + (size_t)tid * 512);
    for (int k4 = 0; k4 < 128; ++k4) {
        const float4 w = wr[k4];
        acc += sx[k4 * 4] * w.x + sx[k4 * 4 + 1] * w.y + sx[k4 * 4 + 2] * w.z + sx[k4 * 4 + 3] * w.w;
    }
    red[tid] = acc; red[256 + tid] = acc * acc;
    __syncthreads();
    for (int s = 128; s > 0; s >>= 1) {
        if (tid < s) { red[tid] += red[tid + s]; red[256 + tid] += red[256 + tid + s]; }
        __syncthreads();
    }
    const float mu = red[0] * (1.f / 256.f);
    float var = red[256] * (1.f / 256.f) - mu * mu;
    if (var < 0.f) var = 0.f;
    const float xn = (acc - mu) * rsqrtf(var + 1e-5f);
    const float yv = xn * lnW[tid] + lnB[tid];
    const float g = 0.5f * yv * (1.0f + erff(yv * 0.70710678118654752f));
    rW[(size_t)row * 256 + tid] = f2bf(g);
}

// ---------------------------------------------------------------------------
// pred_sem = mask(hseq) @ spW^T + spb  (fp32 vector math)
// ---------------------------------------------------------------------------
__global__ void k_pred(const float* __restrict__ hseq, const int* __restrict__ wlens,
                       const float* __restrict__ spW, const float* __restrict__ spb,
                       float* __restrict__ out)
{
    __shared__ float sh[256];
    const int tid = threadIdx.x;
    const int rw = blockIdx.x;
    const int b = rw / 100, w = rw - b * 100;
    int wl = wlens[b]; if (wl < 1) wl = 1;
    const bool valid = (w < wl);
    sh[tid] = valid ? hseq[(size_t)rw * 256 + tid] : 0.f;
    __syncthreads();
    for (int o = tid; o < 512; o += 256) {
        float acc = spb[o];
        const float4* wr = (const float4*)(spW + (size_t)o * 256);
        for (int k4 = 0; k4 < 64; ++k4) {
            const float4 wv = wr[k4];
            acc += sh[k4 * 4] * wv.x + sh[k4 * 4 + 1] * wv.y + sh[k4 * 4 + 2] * wv.z + sh[k4 * 4 + 3] * wv.w;
        }
        out[PS_OFF + (size_t)rw * 512 + o] = acc;
    }
}

__global__ void k_xlens(const int* __restrict__ x_lens, float* __restrict__ out)
{
    const int tid = threadIdx.x;
    if (tid < 16) out[XL_OFF + tid] = (float)x_lens[tid];
}

// Pre-cast fpW (512x512 fp32) -> bf16
__global__ void k_cvt(const float* __restrict__ src, u16* __restrict__ dst)
{
    const int e = blockIdx.x * 256 + threadIdx.x;   // 65536 float4s
    const float4 v = *(const float4*)(src + (size_t)e * 4);
    u32* d = (u32*)(dst + (size_t)e * 4);
    d[0] = pk2(v.x, v.y);
    d[1] = pk2(v.z, v.w);
}

// Zero flags + frame h ring + word h ring: bytes [0, 950272) = 928x256 u32.
__global__ void k_init(u32* __restrict__ p)
{
    p[blockIdx.x * 256 + threadIdx.x] = 0u;
}

// ---------------------------------------------------------------------------
extern "C" void kernel_launch(void* const* d_in, const int* in_sizes, int n_in,
                              void* d_out, int out_size, void* d_ws, size_t ws_size,
                              hipStream_t stream)
{
    (void)in_sizes; (void)n_in; (void)out_size; (void)ws_size;
    const float* x    = (const float*)d_in[0];
    const int* x_lens = (const int*)d_in[1];
    const int* wstart = (const int*)d_in[2];
    const int* wend   = (const int*)d_in[3];
    const int* wlen   = (const int*)d_in[4];
    const int* tailp  = (const int*)d_in[5];
    const float* Wih0 = (const float*)d_in[6];
    const float* Whh0 = (const float*)d_in[7];
    const float* b0   = (const float*)d_in[8];
    const float* Wih1 = (const float*)d_in[9];
    const float* Whh1 = (const float*)d_in[10];
    const float* b1   = (const float*)d_in[11];
    const float* Wih2 = (const float*)d_in[12];
    const float* Whh2 = (const float*)d_in[13];
    const float* b2   = (const float*)d_in[14];
    const float* fpW  = (const float*)d_in[15];
    const float* fpb  = (const float*)d_in[16];
    const float* wpW  = (const float*)d_in[17];
    const float* wpb  = (const float*)d_in[18];
    const float* lnW  = (const float*)d_in[19];
    const float* lnB  = (const float*)d_in[20];
    const float* wWih = (const float*)d_in[21];
    const float* wWhh = (const float*)d_in[22];
    const float* wb   = (const float*)d_in[23];
    const float* spW  = (const float*)d_in[24];
    const float* spb  = (const float*)d_in[25];

    float* out = (float*)d_out;
    char* ws = (char*)d_ws;
    int* flags  = (int*)(ws + WS_FLAGS);
    u16* hbufF  = (u16*)(ws + WS_HBUF_F);
    u16* hbufW  = (u16*)(ws + WS_HBUF_W);
    float* reps = (float*)(ws + WS_REPS);
    u16* rW     = (u16*)(ws + WS_RW);
    float* hseq = (float*)(ws + WS_HSEQ);
    u16* fpWb   = (u16*)(ws + WS_FPWB);

    k_init<<<928, 256, 0, stream>>>((u32*)d_ws);
    k_cvt<<<256, 256, 0, stream>>>(fpW, fpWb);
    k_frame_lstm<<<192, 128, 0, stream>>>(x, Wih0, Whh0, b0, Wih1, Whh1, b1,
                                          Wih2, Whh2, b2, hbufF, flags, out);
    k_pool<<<1600, 256, 0, stream>>>(out, x_lens, wstart, wend, wlen, tailp, reps);
    k_frame_proj<<<2000, 256, 0, stream>>>(out, x_lens, fpWb, fpb);  // after k_pool (in-place)
    k_word_proj<<<1600, 256, 0, stream>>>(reps, wpW, wpb, lnW, lnB, rW);
    k_word_lstm<<<8, 512, 0, stream>>>(rW, wWih, wWhh, wb, hbufW, hseq);
    k_pred<<<1600, 256, 0, stream>>>(hseq, wlen, spW, spb, out);
    k_xlens<<<1, 64, 0, stream>>>(x_lens, out);
}

// Round 5
// 10148.916 us; speedup vs baseline: 1.1106x; 1.1106x over previous
//
#include <hip/hip_runtime.h>
#include <math.h>

typedef unsigned short u16;
typedef unsigned int   u32;
typedef unsigned long long u64;
typedef __attribute__((ext_vector_type(8))) short short8;
typedef __attribute__((ext_vector_type(4))) float f32x4;
typedef __attribute__((ext_vector_type(4))) unsigned int u32x4;

__device__ __forceinline__ u16 f2bf(float f) {
    u32 u = __float_as_uint(f);
    u32 r = (u + 0x7fffu + ((u >> 16) & 1u)) >> 16;
    return (u16)r;
}
__device__ __forceinline__ u32 pk2(float a, float b) {
    return ((u32)f2bf(a)) | (((u32)f2bf(b)) << 16);
}
__device__ __forceinline__ float sigm(float x) { return 1.f / (1.f + __expf(-x)); }
__device__ __forceinline__ f32x4 mfma16(short8 a, short8 b, f32x4 c) {
    return __builtin_amdgcn_mfma_f32_16x16x32_bf16(a, b, c, 0, 0, 0);
}
__device__ __forceinline__ short8 ld8bf(const float* p) {
    short8 r;
#pragma unroll
    for (int j = 0; j < 8; ++j) r[j] = (short)f2bf(p[j]);
    return r;
}
// 16B cache-bypassing load/store straight at the coherence point.
__device__ __forceinline__ u32x4 ldg16cv4(const u16* p) {
    u32x4 r;
    asm volatile("global_load_dwordx4 %0, %1, off sc0 sc1" : "=v"(r) : "v"(p));
    return r;
}
__device__ __forceinline__ void stg16cv(u16* p, u32x4 v) {
    asm volatile("global_store_dwordx4 %0, %1, off sc0 sc1" :: "v"(p), "v"(v) : "memory");
}
__device__ __forceinline__ void waitvm() {
    asm volatile("s_waitcnt vmcnt(0)" ::: "memory");
}
// NOT-decode a published chunk into LDS (16B aligned).
__device__ __forceinline__ void st_not16(u16* dst, u32x4 w) {
    u32x4 d; d[0] = ~w[0]; d[1] = ~w[1]; d[2] = ~w[2]; d[3] = ~w[3];
    *(u32x4*)dst = d;
}
__device__ __forceinline__ void st_zero16(u16* dst) {
    u32x4 d = {0u, 0u, 0u, 0u};
    *(u32x4*)dst = d;
}

#define FLAG_STRIDE 16   /* ints -> 64B per flag slot */
#define BIGF (1 << 26)
#define XL_OFF 16384000
#define PS_OFF 16384016

// ws layout (bytes)
#define WS_FLAGS   0        /* flag slots (frame: 0..191, word: 192..223), 32768 B */
#define WS_HBUF_F  32768    /* 3 layers x 16 slots x 16KB = 786432 -> 819200 */
#define WS_HBUF_W  819200   /* 16 slots x 8KB = 131072 -> 950272 */
#define WS_REPS    950272   /* 1600x512 fp32 = 3276800 -> 4227072 */
#define WS_RW      4227072  /* 1600x256 bf16 = 819200 -> 5046272 */
#define WS_HSEQ    5046272  /* 1600x256 fp32 = 1638400 -> 6684672 */
#define WS_FPWB    6684672  /* 512x512 bf16 = 524288 -> 7208960 */

// ---------------------------------------------------------------------------
// Persistent 3-layer frame LSTM. 192 WGs (64/layer), 128 threads (the proven
// round-0 shape, flag-poll sync). Delta vs round-0: NO-ACK publish.
// Producers publish ~pk (NOT-encoded bf16 pair; 0 == "unwritten" since
// pk==0xFFFFFFFF would need bf16 -NaN, impossible for |h|<1) and store the
// step flag IMMEDIATELY (no waitvm ack) -- the h-stores are issued before
// the flag on the same wave, so they normally reach the coherence point
// first; the consumer validates each 16B chunk nonzero after its (single)
// fetch and re-loads only rare stragglers. Removes one MALL round trip
// (store-ack) from every step of the recurrence critical path.
// Ring-16; producers re-arm (zero) slot (t+8)&15 each step, gated by a
// lazily-cached next-layer progress check (fn >= t-7). Own-peer skew <=1
// (flag poll each step) and cross-layer skew <=7 make re-arm race-free.
// ---------------------------------------------------------------------------
template<int KTIN, bool L0, bool HASNEXT>
__device__ __forceinline__ void frame_body(
    const int layer, const int kwg,
    const float* __restrict__ Wih, const float* __restrict__ Whh, const float* __restrict__ bias,
    const float* __restrict__ x, u16* __restrict__ hbuf, int* __restrict__ flags,
    float* __restrict__ h3out, float* sC, u16* sxpad, u16* AsIn, u16* AsOwn)
{
    const int tid  = threadIdx.x;
    const int lane = tid & 63;
    const int wave = tid >> 6;
    const int n16  = lane & 15;
    const int quad = lane >> 4;
    const int koff = quad * 8;

    if (L0) {                                            // zero the x pad cols [80,96)
        for (int e = tid; e < 256; e += 128) sxpad[(e >> 4) * 96 + 80 + (e & 15)] = 0;
    }

    // B fragments in registers. wave0 -> tile (i|f), wave1 -> tile (g|o).
    const int grow = wave * 1024 + ((n16 >> 3) * 512) + kwg * 8 + (n16 & 7);
    short8 bfr[KTIN + 16];
#pragma unroll
    for (int kt = 0; kt < KTIN; ++kt) {
        short8 v = {0,0,0,0,0,0,0,0};
        const int k = kt * 32 + koff;
        if (L0) { if (k + 8 <= 80) v = ld8bf(Wih + grow * 80 + k); }
        else    { v = ld8bf(Wih + (size_t)grow * 512 + k); }
        bfr[kt] = v;
    }
#pragma unroll
    for (int kt = 0; kt < 16; ++kt)
        bfr[KTIN + kt] = ld8bf(Whh + (size_t)grow * 512 + kt * 32 + koff);

    // gate phase (tid<64): 2 (batch,col) values per lane; c-state in registers
    const int gb = tid & 15;
    const int gp4 = (tid >> 4) & 3;
    const int c0 = kwg * 8 + gp4 * 2;
    const float bI0 = bias[c0],        bI1 = bias[c0 + 1];
    const float bF0 = bias[512 + c0],  bF1 = bias[512 + c0 + 1];
    const float bG0 = bias[1024 + c0], bG1 = bias[1024 + c0 + 1];
    const float bO0 = bias[1536 + c0], bO1 = bias[1536 + c0 + 1];
    float cp0 = 0.f, cp1 = 0.f;

    int* myflag   = flags + (layer * 64 + kwg) * FLAG_STRIDE;
    const int* fP = flags + ((layer > 0 ? layer - 1 : 0) * 64) * FLAG_STRIDE;
    const int* fO = flags + (layer * 64) * FLAG_STRIDE;
    const int* fN = flags + ((layer + 1) * 64) * FLAG_STRIDE;  // valid only if HASNEXT
    int fnc = 0;                                     // cached next-layer progress (wave0)
    u16* lbase = hbuf + (size_t)layer * 16 * 8192;
    const u16* pbase = hbuf + (size_t)(layer > 0 ? layer - 1 : 0) * 16 * 8192;
    __syncthreads();

    for (int t = 0; t < 2000; ++t) {
        // ---- wave0: flag poll (prev layer + own peers), then gated re-arm ----
        if (wave == 0) {
            int guard = 0;
            for (;;) {
                const int fp = L0 ? BIGF
                    : __hip_atomic_load(fP + lane * FLAG_STRIDE, __ATOMIC_RELAXED, __HIP_MEMORY_SCOPE_AGENT);
                const int fo = __hip_atomic_load(fO + lane * FLAG_STRIDE, __ATOMIC_RELAXED, __HIP_MEMORY_SCOPE_AGENT);
                if (__all((fp >= t + 1) && (fo >= t))) break;
                if (++guard > (1 << 22)) break;
                __builtin_amdgcn_s_sleep(1);
            }
            if (HASNEXT && !__all(fnc >= t - 7)) {   // ring anti-dep, lazily refreshed
                int g2 = 0;
                do {
                    fnc = __hip_atomic_load(fN + lane * FLAG_STRIDE, __ATOMIC_RELAXED, __HIP_MEMORY_SCOPE_AGENT);
                    if (__all(fnc >= t - 7)) break;
                    __builtin_amdgcn_s_sleep(2);
                } while (++g2 < (1 << 22));
            }
            if (lane < 16) {                         // re-arm slot (t+8)&15: own 8 cols x 16 rows
                u32x4 zz = {0u, 0u, 0u, 0u};
                stg16cv(lbase + ((size_t)((t + 8) & 15)) * 8192 + lane * 512 + kwg * 8, zz);
            }
        }
        __syncthreads();

        // ---- x loads (L0) ----
        float4 xv0, xv1, xv2;
        const int e0 = tid, e1 = tid + 128, e2 = tid + 256;
        if (L0) {
            xv0 = *(const float4*)(x + ((size_t)(e0 / 20) * 2000 + t) * 80 + (e0 % 20) * 4);
            xv1 = *(const float4*)(x + ((size_t)(e1 / 20) * 2000 + t) * 80 + (e1 % 20) * 4);
            if (e2 < 320)
                xv2 = *(const float4*)(x + ((size_t)(e2 / 20) * 2000 + t) * 80 + (e2 % 20) * 4);
        }

        // ---- data fetch + validate: [0..7]=hin (prev h_t), [8..15]=own h_{t-1} ----
        u32x4 v[16];
        const u16* hin  = pbase + ((size_t)(t & 15)) * 8192;
        const u16* hown = lbase + ((size_t)((t - 1) & 15)) * 8192;
        u32 pend = (L0 ? 0u : 0x00FFu) | (t > 0 ? 0xFF00u : 0u);
        int rounds = 0;
        while (pend) {
#pragma unroll
            for (int i = 0; i < 8; ++i)
                if (!L0 && (pend & (1u << i)))   v[i]     = ldg16cv4(hin  + (tid + 128 * i) * 8);
#pragma unroll
            for (int i = 0; i < 8; ++i)
                if (pend & (0x100u << i))        v[8 + i] = ldg16cv4(hown + (tid + 128 * i) * 8);
            waitvm();
#pragma unroll
            for (int i = 0; i < 16; ++i)
                if ((pend & (1u << i)) && v[i][0] && v[i][1] && v[i][2] && v[i][3])
                    pend &= ~(1u << i);
            if (pend) __builtin_amdgcn_s_sleep(2);   // rare: flag beat the data
            if (++rounds > (1 << 20)) break;
        }

        // ---- stage into LDS (NOT-decode) ----
        if (L0) {
            u32* d0 = (u32*)(sxpad + (e0 / 20) * 96 + (e0 % 20) * 4);
            d0[0] = pk2(xv0.x, xv0.y); d0[1] = pk2(xv0.z, xv0.w);
            u32* d1 = (u32*)(sxpad + (e1 / 20) * 96 + (e1 % 20) * 4);
            d1[0] = pk2(xv1.x, xv1.y); d1[1] = pk2(xv1.z, xv1.w);
            if (e2 < 320) {
                u32* d2 = (u32*)(sxpad + (e2 / 20) * 96 + (e2 % 20) * 4);
                d2[0] = pk2(xv2.x, xv2.y); d2[1] = pk2(xv2.z, xv2.w);
            }
        }
#pragma unroll
        for (int i = 0; i < 8; ++i) {
            const int c = tid + 128 * i;
            const int row = c >> 6, col8 = (c & 63) << 3;
            if (!L0) st_not16(AsIn + row * 520 + col8, v[i]);
            if (t > 0) st_not16(AsOwn + row * 520 + col8, v[8 + i]);
            else       st_zero16(AsOwn + row * 520 + col8);
        }
        __syncthreads();

        // ---- gate GEMM ----
        f32x4 acc[4] = {{0,0,0,0},{0,0,0,0},{0,0,0,0},{0,0,0,0}};
#pragma unroll
        for (int kt = 0; kt < KTIN; ++kt) {
            short8 a;
            if (L0) a = *(const short8*)(sxpad + n16 * 96 + kt * 32 + koff);
            else    a = *(const short8*)(AsIn + n16 * 520 + kt * 32 + koff);
            acc[kt & 3] = mfma16(a, bfr[kt], acc[kt & 3]);
        }
#pragma unroll
        for (int kt = 0; kt < 16; ++kt) {
            short8 a = *(const short8*)(AsOwn + n16 * 520 + kt * 32 + koff);
            acc[(KTIN + kt) & 3] = mfma16(a, bfr[KTIN + kt], acc[(KTIN + kt) & 3]);
        }
        const f32x4 C = acc[0] + acc[1] + acc[2] + acc[3];
#pragma unroll
        for (int r = 0; r < 4; ++r)
            sC[(wave * 16 + quad * 4 + r) * 17 + n16] = C[r];   // [wave*16+batch][gate]
        __syncthreads();

        // ---- gate math (tid<64) + NO-ACK publish ----
        if (tid < 64) {
            const int b = gb, p = gp4;
            float hn0, hn1;
            {
                const float gi = sC[b * 17 + p * 2]            + bI0;
                const float gf = sC[b * 17 + 8 + p * 2]        + bF0;
                const float gg = sC[(16 + b) * 17 + p * 2]     + bG0;
                const float go = sC[(16 + b) * 17 + 8 + p * 2] + bO0;
                const float cn = sigm(gf) * cp0 + sigm(gi) * tanhf(gg);
                hn0 = sigm(go) * tanhf(cn);
                cp0 = cn;
            }
            {
                const float gi = sC[b * 17 + p * 2 + 1]            + bI1;
                const float gf = sC[b * 17 + 8 + p * 2 + 1]        + bF1;
                const float gg = sC[(16 + b) * 17 + p * 2 + 1]     + bG1;
                const float go = sC[(16 + b) * 17 + 8 + p * 2 + 1] + bO1;
                const float cn = sigm(gf) * cp1 + sigm(gi) * tanhf(gg);
                hn1 = sigm(go) * tanhf(cn);
                cp1 = cn;
            }
            const u32 enc = ~(((u32)f2bf(hn0)) | (((u32)f2bf(hn1)) << 16));
            u32* hd = (u32*)(lbase + ((size_t)(t & 15)) * 8192) + b * 256 + kwg * 4 + p;
            __hip_atomic_store(hd, enc, __ATOMIC_RELAXED, __HIP_MEMORY_SCOPE_AGENT);
            asm volatile("" ::: "memory");   // keep flag store after h stores
            if (tid == 0)
                __hip_atomic_store(myflag, t + 1, __ATOMIC_RELAXED, __HIP_MEMORY_SCOPE_AGENT);
            if (!HASNEXT) {   // layer-2 fp32 output, off the recurrence path
                float* hp = h3out + ((size_t)(b * 2000 + t)) * 512 + kwg * 8 + p * 2;
                hp[0] = hn0; hp[1] = hn1;
            }
        }
    }
}

__global__ __launch_bounds__(128, 1) void k_frame_lstm(
    const float* __restrict__ x,
    const float* __restrict__ Wih0, const float* __restrict__ Whh0, const float* __restrict__ b0,
    const float* __restrict__ Wih1, const float* __restrict__ Whh1, const float* __restrict__ b1,
    const float* __restrict__ Wih2, const float* __restrict__ Whh2, const float* __restrict__ b2,
    u16* hbuf, int* flags, float* h3out)
{
    __shared__ __align__(16) u16 sxpad[16 * 96];
    __shared__ __align__(16) u16 AsIn[16 * 520];
    __shared__ __align__(16) u16 AsOwn[16 * 520];
    __shared__ float sC[32 * 17];
    const int wgid = blockIdx.x;
    const int layer = wgid >> 6;
    const int kwg = wgid & 63;
    if (layer == 0)      frame_body<3,  true,  true >(0, kwg, Wih0, Whh0, b0, x, hbuf, flags, h3out, sC, sxpad, AsIn, AsOwn);
    else if (layer == 1) frame_body<16, false, true >(1, kwg, Wih1, Whh1, b1, x, hbuf, flags, h3out, sC, sxpad, AsIn, AsOwn);
    else                 frame_body<16, false, false>(2, kwg, Wih2, Whh2, b2, x, hbuf, flags, h3out, sC, sxpad, AsIn, AsOwn);
}

// ---------------------------------------------------------------------------
// Persistent word LSTM: 32 WGs x 128 threads, 100 steps, H=256 (round-0
// shape). Same no-ack protocol: NOT-encoded publish, immediate flag,
// consumer-side per-chunk validation. Ring-16, ungated re-arm (skew <=1).
// ---------------------------------------------------------------------------
__global__ __launch_bounds__(128, 1) void k_word_lstm(
    const u16* __restrict__ rW, const float* __restrict__ Wih,
    const float* __restrict__ Whh, const float* __restrict__ bias,
    u16* __restrict__ hbufw, int* __restrict__ flags, float* __restrict__ hseq)
{
    __shared__ float sC[32 * 17];
    const int tid = threadIdx.x;
    const int lane = tid & 63;
    const int wave = tid >> 6;
    const int n16 = lane & 15;
    const int quad = lane >> 4;
    const int koff = quad * 8;
    const int kwg = blockIdx.x;  // 0..31

    const int grow = wave * 512 + ((n16 >> 3) * 256) + kwg * 8 + (n16 & 7);
    short8 bfr[16];
#pragma unroll
    for (int kt = 0; kt < 8; ++kt) bfr[kt]     = ld8bf(Wih + (size_t)grow * 256 + kt * 32 + koff);
#pragma unroll
    for (int kt = 0; kt < 8; ++kt) bfr[8 + kt] = ld8bf(Whh + (size_t)grow * 256 + kt * 32 + koff);
    const int gb = tid & 15;
    const int gp4 = (tid >> 4) & 3;
    const int c0 = kwg * 8 + gp4 * 2;
    const float bI0 = bias[c0],       bI1 = bias[c0 + 1];
    const float bF0 = bias[256 + c0], bF1 = bias[256 + c0 + 1];
    const float bG0 = bias[512 + c0], bG1 = bias[512 + c0 + 1];
    const float bO0 = bias[768 + c0], bO1 = bias[768 + c0 + 1];
    float cp0 = 0.f, cp1 = 0.f;
    const int* fO = flags + 192 * FLAG_STRIDE;
    int* myflag   = flags + (192 + kwg) * FLAG_STRIDE;
    __syncthreads();
    const int aoff = n16 * 256 + koff;

    for (int t = 0; t < 100; ++t) {
        if (wave == 0) {
            int guard = 0;
            for (;;) {
                const int fo = (lane < 32)
                    ? __hip_atomic_load(fO + lane * FLAG_STRIDE, __ATOMIC_RELAXED, __HIP_MEMORY_SCOPE_AGENT)
                    : BIGF;
                if (__all(fo >= t)) break;
                if (++guard > (1 << 22)) break;
                __builtin_amdgcn_s_sleep(1);
            }
            if (lane < 16) {                 // re-arm slot (t+8)&15: own 8 cols x 16 rows
                u32x4 zz = {0u, 0u, 0u, 0u};
                stg16cv(hbufw + ((size_t)((t + 8) & 15)) * 4096 + lane * 256 + kwg * 8, zz);
            }
        }
        __syncthreads();

        // own h_{t-1}: 8 validated bypass chunks per lane (row n16 fragments)
        const u16* hown = hbufw + ((size_t)((t - 1) & 15)) * 4096;
        u32x4 hv[8];
        u32 pend = (t > 0) ? 0xFFu : 0u;
        int rounds = 0;
        while (pend) {
#pragma unroll
            for (int kt = 0; kt < 8; ++kt)
                if (pend & (1u << kt)) hv[kt] = ldg16cv4(hown + aoff + kt * 32);
            waitvm();
#pragma unroll
            for (int kt = 0; kt < 8; ++kt)
                if ((pend & (1u << kt)) && hv[kt][0] && hv[kt][1] && hv[kt][2] && hv[kt][3])
                    pend &= ~(1u << kt);
            if (pend) __builtin_amdgcn_s_sleep(2);
            if (++rounds > (1 << 20)) break;
        }

        f32x4 acc[4] = {{0,0,0,0},{0,0,0,0},{0,0,0,0},{0,0,0,0}};
#pragma unroll
        for (int kt = 0; kt < 8; ++kt) {
            short8 a = *(const short8*)(rW + ((size_t)(n16 * 100 + t)) * 256 + koff + kt * 32);
            acc[kt & 3] = mfma16(a, bfr[kt], acc[kt & 3]);
        }
        if (t > 0) {
#pragma unroll
            for (int kt = 0; kt < 8; ++kt) {
                u32x4 d; d[0] = ~hv[kt][0]; d[1] = ~hv[kt][1]; d[2] = ~hv[kt][2]; d[3] = ~hv[kt][3];
                short8 a = __builtin_bit_cast(short8, d);
                acc[kt & 3] = mfma16(a, bfr[8 + kt], acc[kt & 3]);
            }
        }
        const f32x4 C = acc[0] + acc[1] + acc[2] + acc[3];
#pragma unroll
        for (int r = 0; r < 4; ++r) sC[(wave * 16 + quad * 4 + r) * 17 + n16] = C[r];
        __syncthreads();

        if (tid < 64) {
            const int b = gb, p = gp4;
            float hn0, hn1;
            {
                const float gi = sC[b * 17 + p * 2]            + bI0;
                const float gf = sC[b * 17 + 8 + p * 2]        + bF0;
                const float gg = sC[(16 + b) * 17 + p * 2]     + bG0;
                const float go = sC[(16 + b) * 17 + 8 + p * 2] + bO0;
                const float cn = sigm(gf) * cp0 + sigm(gi) * tanhf(gg);
                hn0 = sigm(go) * tanhf(cn);
                cp0 = cn;
            }
            {
                const float gi = sC[b * 17 + p * 2 + 1]            + bI1;
                const float gf = sC[b * 17 + 8 + p * 2 + 1]        + bF1;
                const float gg = sC[(16 + b) * 17 + p * 2 + 1]     + bG1;
                const float go = sC[(16 + b) * 17 + 8 + p * 2 + 1] + bO1;
                const float cn = sigm(gf) * cp1 + sigm(gi) * tanhf(gg);
                hn1 = sigm(go) * tanhf(cn);
                cp1 = cn;
            }
            const u32 enc = ~(((u32)f2bf(hn0)) | (((u32)f2bf(hn1)) << 16));
            u32* hd = (u32*)(hbufw + ((size_t)(t & 15)) * 4096) + b * 128 + kwg * 4 + p;
            __hip_atomic_store(hd, enc, __ATOMIC_RELAXED, __HIP_MEMORY_SCOPE_AGENT);
            asm volatile("" ::: "memory");
            if (tid == 0)
                __hip_atomic_store(myflag, t + 1, __ATOMIC_RELAXED, __HIP_MEMORY_SCOPE_AGENT);
            float* hp = hseq + ((size_t)(b * 100 + t)) * 256 + kwg * 8 + p * 2;
            hp[0] = hn0; hp[1] = hn1;
        }
        __syncthreads();   // protect sC from next iteration
    }
}

// ---------------------------------------------------------------------------
// Ragged tail-mean pooling from fp32 h3 (in d_out): reps fp32 (ws)
// ---------------------------------------------------------------------------
__global__ void k_pool(const float* __restrict__ h3, const int* __restrict__ x_lens,
                       const int* __restrict__ wstarts, const int* __restrict__ wends,
                       const int* __restrict__ wlens, const int* __restrict__ tailp,
                       float* __restrict__ reps)
{
    const int rw = blockIdx.x;
    const int b = rw / 100, w = rw - b * 100;
    const int tid = threadIdx.x;
    const int xl = x_lens[b];
    const int we = wends[rw];
    const int s0 = wstarts[rw];
    const int wl = wlens[b];
    const int tail = tailp[0];
    int ef = we < xl ? we : xl;
    int sf = s0 > 0 ? s0 : 0;
    int i0 = ef - tail; if (i0 < sf) i0 = sf;
    const bool valid = (w < wl) && (we > 0) && (ef > sf) && (ef > i0);
    float a0 = 0.f, a1 = 0.f;
    if (valid) {
        for (int t = i0; t < ef; ++t) {
            const float* hp = h3 + ((size_t)(b * 2000 + t)) * 512;
            a0 += hp[tid];
            a1 += hp[tid + 256];
        }
        const float inv = 1.f / (float)(ef - i0);
        a0 *= inv; a1 *= inv;
    }
    reps[(size_t)rw * 512 + tid] = a0;
    reps[(size_t)rw * 512 + tid + 256] = a1;
}

// ---------------------------------------------------------------------------
// In-place frame projection: y[b,t,:] = mask(h3[b,t,:]) @ fpW^T + fpb (fp32)
// ---------------------------------------------------------------------------
__global__ __launch_bounds__(256, 2) void k_frame_proj(
    float* __restrict__ y, const int* __restrict__ x_lens,
    const u16* __restrict__ fpWb, const float* __restrict__ fpb)
{
    __shared__ __align__(16) u16 As[16 * 520];
    const int tid = threadIdx.x, lane = tid & 63, wave = tid >> 6;
    const int n16 = lane & 15, quad = lane >> 4, koff = quad * 8;
    const int blk = blockIdx.x;          // 2000 blocks: 125 per batch
    const int b = blk / 125;
    const int t0 = (blk - b * 125) * 16;
    const int xl = x_lens[b];
    for (int c = tid; c < 2048; c += 256) {      // 16 rows x 128 float4
        const int row = c >> 7;
        const int q = c & 127;
        const int t = t0 + row;
        float4 v = {0.f, 0.f, 0.f, 0.f};
        if (t < xl) v = *(const float4*)(y + ((size_t)(b * 2000 + t)) * 512 + q * 4);
        u32* d = (u32*)(As + row * 520 + q * 4);
        d[0] = pk2(v.x, v.y);
        d[1] = pk2(v.z, v.w);
    }
    __syncthreads();
    const size_t rowbase = (size_t)b * 2000 + t0;
    for (int ct = 0; ct < 8; ++ct) {
        const int col0 = (wave * 8 + ct) * 16;
        f32x4 acc = {0, 0, 0, 0};
#pragma unroll
        for (int kt = 0; kt < 16; ++kt) {
            short8 a = *(const short8*)(As + n16 * 520 + kt * 32 + koff);
            short8 wv = *(const short8*)(fpWb + ((size_t)(col0 + n16)) * 512 + kt * 32 + koff);
            acc = mfma16(a, wv, acc);
        }
        const float bn = fpb[col0 + n16];
#pragma unroll
        for (int r = 0; r < 4; ++r) {
            const int m = quad * 4 + r;
            y[(rowbase + m) * 512 + col0 + n16] = acc[r] + bn;
        }
    }
}

// ---------------------------------------------------------------------------
// word_proj: Linear(512->256) + LayerNorm + exact GELU per (b,w) row.
// ---------------------------------------------------------------------------
__global__ void k_word_proj(const float* __restrict__ reps, const float* __restrict__ wpW,
                            const float* __restrict__ wpb, const float* __restrict__ lnW,
                            const float* __restrict__ lnB, u16* __restrict__ rW)
{
    __shared__ float sx[512];
    __shared__ float red[512];
    const int tid = threadIdx.x;
    const int row = blockIdx.x;
    for (int k = tid; k < 512; k += 256) sx[k] = reps[(size_t)row * 512 + k];
    __syncthreads();
    float acc = wpb[tid];
    const float4* wr = (const float4*)(wpW + (size_t)tid * 512);
    for (int k4 = 0; k4 < 128; ++k4) {
        const float4 w = wr[k4];
        acc += sx[k4 * 4] * w.x + sx[k4 * 4 + 1] * w.y + sx[k4 * 4 + 2] * w.z + sx[k4 * 4 + 3] * w.w;
    }
    red[tid] = acc; red[256 + tid] = acc * acc;
    __syncthreads();
    for (int s = 128; s > 0; s >>= 1) {
        if (tid < s) { red[tid] += red[tid + s]; red[256 + tid] += red[256 + tid + s]; }
        __syncthreads();
    }
    const float mu = red[0] * (1.f / 256.f);
    float var = red[256] * (1.f / 256.f) - mu * mu;
    if (var < 0.f) var = 0.f;
    const float xn = (acc - mu) * rsqrtf(var + 1e-5f);
    const float yv = xn * lnW[tid] + lnB[tid];
    const float g = 0.5f * yv * (1.0f + erff(yv * 0.70710678118654752f));
    rW[(size_t)row * 256 + tid] = f2bf(g);
}

// ---------------------------------------------------------------------------
// pred_sem = mask(hseq) @ spW^T + spb  (fp32 vector math)
// ---------------------------------------------------------------------------
__global__ void k_pred(const float* __restrict__ hseq, const int* __restrict__ wlens,
                       const float* __restrict__ spW, const float* __restrict__ spb,
                       float* __restrict__ out)
{
    __shared__ float sh[256];
    const int tid = threadIdx.x;
    const int rw = blockIdx.x;
    const int b = rw / 100, w = rw - b * 100;
    int wl = wlens[b]; if (wl < 1) wl = 1;
    const bool valid = (w < wl);
    sh[tid] = valid ? hseq[(size_t)rw * 256 + tid] : 0.f;
    __syncthreads();
    for (int o = tid; o < 512; o += 256) {
        float acc = spb[o];
        const float4* wr = (const float4*)(spW + (size_t)o * 256);
        for (int k4 = 0; k4 < 64; ++k4) {
            const float4 wv = wr[k4];
            acc += sh[k4 * 4] * wv.x + sh[k4 * 4 + 1] * wv.y + sh[k4 * 4 + 2] * wv.z + sh[k4 * 4 + 3] * wv.w;
        }
        out[PS_OFF + (size_t)rw * 512 + o] = acc;
    }
}

__global__ void k_xlens(const int* __restrict__ x_lens, float* __restrict__ out)
{
    const int tid = threadIdx.x;
    if (tid < 16) out[XL_OFF + tid] = (float)x_lens[tid];
}

// Pre-cast fpW (512x512 fp32) -> bf16
__global__ void k_cvt(const float* __restrict__ src, u16* __restrict__ dst)
{
    const int e = blockIdx.x * 256 + threadIdx.x;   // 65536 float4s
    const float4 v = *(const float4*)(src + (size_t)e * 4);
    u32* d = (u32*)(dst + (size_t)e * 4);
    d[0] = pk2(v.x, v.y);
    d[1] = pk2(v.z, v.w);
}

// Zero flags + frame h ring + word h ring: bytes [0, 950272) = 928x256 u32.
__global__ void k_init(u32* __restrict__ p)
{
    p[blockIdx.x * 256 + threadIdx.x] = 0u;
}

// ---------------------------------------------------------------------------
extern "C" void kernel_launch(void* const* d_in, const int* in_sizes, int n_in,
                              void* d_out, int out_size, void* d_ws, size_t ws_size,
                              hipStream_t stream)
{
    (void)in_sizes; (void)n_in; (void)out_size; (void)ws_size;
    const float* x    = (const float*)d_in[0];
    const int* x_lens = (const int*)d_in[1];
    const int* wstart = (const int*)d_in[2];
    const int* wend   = (const int*)d_in[3];
    const int* wlen   = (const int*)d_in[4];
    const int* tailp  = (const int*)d_in[5];
    const float* Wih0 = (const float*)d_in[6];
    const float* Whh0 = (const float*)d_in[7];
    const float* b0   = (const float*)d_in[8];
    const float* Wih1 = (const float*)d_in[9];
    const float* Whh1 = (const float*)d_in[10];
    const float* b1   = (const float*)d_in[11];
    const float* Wih2 = (const float*)d_in[12];
    const float* Whh2 = (const float*)d_in[13];
    const float* b2   = (const float*)d_in[14];
    const float* fpW  = (const float*)d_in[15];
    const float* fpb  = (const float*)d_in[16];
    const float* wpW  = (const float*)d_in[17];
    const float* wpb  = (const float*)d_in[18];
    const float* lnW  = (const float*)d_in[19];
    const float* lnB  = (const float*)d_in[20];
    const float* wWih = (const float*)d_in[21];
    const float* wWhh = (const float*)d_in[22];
    const float* wb   = (const float*)d_in[23];
    const float* spW  = (const float*)d_in[24];
    const float* spb  = (const float*)d_in[25];

    float* out = (float*)d_out;
    char* ws = (char*)d_ws;
    int* flags  = (int*)(ws + WS_FLAGS);
    u16* hbufF  = (u16*)(ws + WS_HBUF_F);
    u16* hbufW  = (u16*)(ws + WS_HBUF_W);
    float* reps = (float*)(ws + WS_REPS);
    u16* rW     = (u16*)(ws + WS_RW);
    float* hseq = (float*)(ws + WS_HSEQ);
    u16* fpWb   = (u16*)(ws + WS_FPWB);

    k_init<<<928, 256, 0, stream>>>((u32*)d_ws);
    k_cvt<<<256, 256, 0, stream>>>(fpW, fpWb);
    k_frame_lstm<<<192, 128, 0, stream>>>(x, Wih0, Whh0, b0, Wih1, Whh1, b1,
                                          Wih2, Whh2, b2, hbufF, flags, out);
    k_pool<<<1600, 256, 0, stream>>>(out, x_lens, wstart, wend, wlen, tailp, reps);
    k_frame_proj<<<2000, 256, 0, stream>>>(out, x_lens, fpWb, fpb);  // after k_pool (in-place)
    k_word_proj<<<1600, 256, 0, stream>>>(reps, wpW, wpb, lnW, lnB, rW);
    k_word_lstm<<<32, 128, 0, stream>>>(rW, wWih, wWhh, wb, hbufW, flags, hseq);
    k_pred<<<1600, 256, 0, stream>>>(hseq, wlen, spW, spb, out);
    k_xlens<<<1, 64, 0, stream>>>(x_lens, out);
}

// Round 6
// 9664.752 us; speedup vs baseline: 1.1662x; 1.0501x over previous
//
#include <hip/hip_runtime.h>
#include <math.h>

typedef unsigned short u16;
typedef unsigned int   u32;
typedef unsigned long long u64;
typedef __attribute__((ext_vector_type(8))) short short8;
typedef __attribute__((ext_vector_type(4))) float f32x4;

__device__ __forceinline__ u16 f2bf(float f) {
    u32 u = __float_as_uint(f);
    u32 r = (u + 0x7fffu + ((u >> 16) & 1u)) >> 16;
    return (u16)r;
}
__device__ __forceinline__ u32 pk2(float a, float b) {
    return ((u32)f2bf(a)) | (((u32)f2bf(b)) << 16);
}
__device__ __forceinline__ float sigm(float x) { return 1.f / (1.f + __expf(-x)); }
__device__ __forceinline__ f32x4 mfma16(short8 a, short8 b, f32x4 c) {
    return __builtin_amdgcn_mfma_f32_16x16x32_bf16(a, b, c, 0, 0, 0);
}
__device__ __forceinline__ short8 ld8bf(const float* p) {
    short8 r;
#pragma unroll
    for (int j = 0; j < 8; ++j) r[j] = (short)f2bf(p[j]);
    return r;
}
// 16B cache-bypassing load straight from the coherence point.
__device__ __forceinline__ short8 ldg16cv(const u16* p) {
    short8 r;
    asm volatile("global_load_dwordx4 %0, %1, off sc0 sc1" : "=v"(r) : "v"(p));
    return r;
}
__device__ __forceinline__ void waitvm() {
    asm volatile("s_waitcnt vmcnt(0)" ::: "memory");
}
__device__ __forceinline__ void waitvm16() {
    asm volatile("s_waitcnt vmcnt(16)" ::: "memory");
}

#define FLAG_STRIDE 16   /* ints -> 64B per flag slot */
#define BIGF (1 << 26)
#define XL_OFF 16384000
#define PS_OFF 16384016

// ws layout (bytes) -- the proven round-0 layout (ring-8)
#define WS_FLAGS   0        /* frame flags 0..191, word flags 192..223 */
#define WS_HBUF_F  32768    /* 3 layers x 8 slots x 16KB = 393216 */
#define WS_HBUF_W  425984   /* 8 slots x 8KB = 65536 */
#define WS_REPS    491520   /* 1600x512 fp32 = 3276800 */
#define WS_RW      3768320  /* 1600x256 bf16 = 819200 */
#define WS_HSEQ    4587520  /* 1600x256 fp32 = 1638400 */
#define WS_FPWB    6225920  /* 512x512 bf16 = 524288 -> end 6750208 */

// ---------------------------------------------------------------------------
// Persistent 3-layer frame LSTM. 192 WGs (64/layer), 128 threads. Sync
// protocol is round-0's proven scheme VERBATIM (publish -> waitvm ack ->
// flag; consumers poll fp>=t+1, fo>=t, fn>=t-7 then load). Deltas are all
// in the non-sync step body:
//  * NO LDS A-staging: each lane bypass-loads its 32 MFMA A-fragments
//    (16B each, row n16 / col kt*32+koff of the h slot) DIRECTLY into
//    registers -- deletes 16 LDS stores + 32 ds_read_b128 + 1 barrier.
//  * ALL-LANE flag polling (no post-poll barrier): wave1 passing poll(t+1)
//    requires own flag == t+1, which wave0 sets only after its gate-phase
//    sC reads -- so the sC write/read race is flag-ordered, barrier-free.
//  * vmcnt(16) lets the own-h load tail fly under the 16 hin MFMAs;
//    sched_barrier(0) after each waitcnt stops MFMA hoisting (rule #18).
//  * c-state in registers (2 cols/lane on wave0), 1 barrier/step (2 on L0).
// ---------------------------------------------------------------------------
template<int KTIN, bool L0, bool HASNEXT>
__device__ __forceinline__ void frame_body(
    const int layer, const int kwg,
    const float* __restrict__ Wih, const float* __restrict__ Whh, const float* __restrict__ bias,
    const float* __restrict__ x, u16* __restrict__ hbuf, int* __restrict__ flags,
    float* __restrict__ h3out, float* sC, u16* sxpad)
{
    const int tid  = threadIdx.x;
    const int lane = tid & 63;
    const int wave = tid >> 6;
    const int n16  = lane & 15;
    const int quad = lane >> 4;
    const int koff = quad * 8;

    if (L0) {                                            // zero the x pad cols [80,96)
        for (int e = tid; e < 256; e += 128) sxpad[(e >> 4) * 96 + 80 + (e & 15)] = 0;
    }

    // B fragments in registers. wave0 -> tile (i|f), wave1 -> tile (g|o).
    const int grow = wave * 1024 + ((n16 >> 3) * 512) + kwg * 8 + (n16 & 7);
    short8 bfr[KTIN + 16];
#pragma unroll
    for (int kt = 0; kt < KTIN; ++kt) {
        short8 v = {0,0,0,0,0,0,0,0};
        const int k = kt * 32 + koff;
        if (L0) { if (k + 8 <= 80) v = ld8bf(Wih + grow * 80 + k); }
        else    { v = ld8bf(Wih + (size_t)grow * 512 + k); }
        bfr[kt] = v;
    }
#pragma unroll
    for (int kt = 0; kt < 16; ++kt)
        bfr[KTIN + kt] = ld8bf(Whh + (size_t)grow * 512 + kt * 32 + koff);

    // gate phase (tid<64): 2 (batch,col) values per lane; c-state in registers
    const int gb = tid & 15;
    const int gp4 = (tid >> 4) & 3;
    const int c0 = kwg * 8 + gp4 * 2;
    const float bI0 = bias[c0],        bI1 = bias[c0 + 1];
    const float bF0 = bias[512 + c0],  bF1 = bias[512 + c0 + 1];
    const float bG0 = bias[1024 + c0], bG1 = bias[1024 + c0 + 1];
    const float bO0 = bias[1536 + c0], bO1 = bias[1536 + c0 + 1];
    float cp0 = 0.f, cp1 = 0.f;

    int* myflag   = flags + (layer * 64 + kwg) * FLAG_STRIDE;
    const int* fP = flags + ((layer > 0 ? layer - 1 : 0) * 64) * FLAG_STRIDE;
    const int* fO = flags + (layer * 64) * FLAG_STRIDE;
    const int* fN = flags + ((HASNEXT ? layer + 1 : layer) * 64) * FLAG_STRIDE;
    u16* lbase = hbuf + (size_t)layer * 8 * 8192;
    const u16* pbase = hbuf + (size_t)(layer > 0 ? layer - 1 : 0) * 8 * 8192;
    const int abase = n16 * 512 + koff;   // per-lane A-fragment base within a slot
    __syncthreads();

    for (int t = 0; t < 2000; ++t) {
        // ---- ALL-LANE flag poll (round-0 semantics) ----
        {
            int guard = 0;
            for (;;) {
                const int fp = L0 ? BIGF
                    : __hip_atomic_load(fP + lane * FLAG_STRIDE, __ATOMIC_RELAXED, __HIP_MEMORY_SCOPE_AGENT);
                const int fo = __hip_atomic_load(fO + lane * FLAG_STRIDE, __ATOMIC_RELAXED, __HIP_MEMORY_SCOPE_AGENT);
                const int fn = HASNEXT
                    ? __hip_atomic_load(fN + lane * FLAG_STRIDE, __ATOMIC_RELAXED, __HIP_MEMORY_SCOPE_AGENT)
                    : BIGF;
                if (__all((fp >= t + 1) && (fo >= t) && (fn >= t - 7))) break;
                if (++guard > (1 << 22)) break;   // anti-hang escape
                __builtin_amdgcn_s_sleep(1);
            }
        }

        // ---- direct A-fragment loads (no LDS staging) ----
        const u16* hin  = pbase + ((size_t)(t & 7)) * 8192 + abase;
        const u16* hown = lbase + ((size_t)((t + 7) & 7)) * 8192 + abase;
        short8 ain[16], aown[16];
        float4 xv0, xv1, xv2;
        if (L0) {
            const int e0 = tid, e1 = tid + 128, e2 = tid + 256;
            xv0 = *(const float4*)(x + ((size_t)(e0 / 20) * 2000 + t) * 80 + (e0 % 20) * 4);
            xv1 = *(const float4*)(x + ((size_t)(e1 / 20) * 2000 + t) * 80 + (e1 % 20) * 4);
            if (e2 < 320)
                xv2 = *(const float4*)(x + ((size_t)(e2 / 20) * 2000 + t) * 80 + (e2 % 20) * 4);
        } else {
#pragma unroll
            for (int kt = 0; kt < 16; ++kt) ain[kt] = ldg16cv(hin + kt * 32);
        }
        if (t > 0) {
#pragma unroll
            for (int kt = 0; kt < 16; ++kt) aown[kt] = ldg16cv(hown + kt * 32);
        }

        if (L0) {
            waitvm();                                  // x + own-h
            __builtin_amdgcn_sched_barrier(0);
            const int e0 = tid, e1 = tid + 128, e2 = tid + 256;
            u32* d0 = (u32*)(sxpad + (e0 / 20) * 96 + (e0 % 20) * 4);
            d0[0] = pk2(xv0.x, xv0.y); d0[1] = pk2(xv0.z, xv0.w);
            u32* d1 = (u32*)(sxpad + (e1 / 20) * 96 + (e1 % 20) * 4);
            d1[0] = pk2(xv1.x, xv1.y); d1[1] = pk2(xv1.z, xv1.w);
            if (e2 < 320) {
                u32* d2 = (u32*)(sxpad + (e2 / 20) * 96 + (e2 % 20) * 4);
                d2[0] = pk2(xv2.x, xv2.y); d2[1] = pk2(xv2.z, xv2.w);
            }
            __syncthreads();                           // sxpad staging barrier
        } else {
            if (t > 0) waitvm16();                     // hin (16 oldest) done
            else       waitvm();
            __builtin_amdgcn_sched_barrier(0);
        }

        // ---- gate GEMM straight from registers ----
        f32x4 acc[4] = {{0,0,0,0},{0,0,0,0},{0,0,0,0},{0,0,0,0}};
        if (L0) {
#pragma unroll
            for (int kt = 0; kt < KTIN; ++kt) {
                short8 a = *(const short8*)(sxpad + n16 * 96 + kt * 32 + koff);
                acc[kt & 3] = mfma16(a, bfr[kt], acc[kt & 3]);
            }
        } else {
#pragma unroll
            for (int kt = 0; kt < KTIN; ++kt)
                acc[kt & 3] = mfma16(ain[kt], bfr[kt], acc[kt & 3]);
        }
        if (t > 0) {
            if (!L0) { waitvm(); __builtin_amdgcn_sched_barrier(0); }
#pragma unroll
            for (int kt = 0; kt < 16; ++kt)
                acc[(KTIN + kt) & 3] = mfma16(aown[kt], bfr[KTIN + kt], acc[(KTIN + kt) & 3]);
        }
        const f32x4 C = acc[0] + acc[1] + acc[2] + acc[3];
#pragma unroll
        for (int r = 0; r < 4; ++r)
            sC[(wave * 16 + quad * 4 + r) * 17 + n16] = C[r];   // [wave*16+batch][gate]
        __syncthreads();

        // ---- gate math (tid<64) + ack'd publish (round-0 protocol) ----
        if (tid < 64) {
            const int b = gb, p = gp4;
            float hn0, hn1;
            {
                const float gi = sC[b * 17 + p * 2]            + bI0;
                const float gf = sC[b * 17 + 8 + p * 2]        + bF0;
                const float gg = sC[(16 + b) * 17 + p * 2]     + bG0;
                const float go = sC[(16 + b) * 17 + 8 + p * 2] + bO0;
                const float cn = sigm(gf) * cp0 + sigm(gi) * tanhf(gg);
                hn0 = sigm(go) * tanhf(cn);
                cp0 = cn;
            }
            {
                const float gi = sC[b * 17 + p * 2 + 1]            + bI1;
                const float gf = sC[b * 17 + 8 + p * 2 + 1]        + bF1;
                const float gg = sC[(16 + b) * 17 + p * 2 + 1]     + bG1;
                const float go = sC[(16 + b) * 17 + 8 + p * 2 + 1] + bO1;
                const float cn = sigm(gf) * cp1 + sigm(gi) * tanhf(gg);
                hn1 = sigm(go) * tanhf(cn);
                cp1 = cn;
            }
            const u32 pk = ((u32)f2bf(hn0)) | (((u32)f2bf(hn1)) << 16);
            u32* hd = (u32*)(lbase + ((size_t)(t & 7)) * 8192) + b * 256 + kwg * 4 + p;
            __hip_atomic_store(hd, pk, __ATOMIC_RELAXED, __HIP_MEMORY_SCOPE_AGENT);
            waitvm();   // ack at coherence point before flag
            if (tid == 0)
                __hip_atomic_store(myflag, t + 1, __ATOMIC_RELAXED, __HIP_MEMORY_SCOPE_AGENT);
            if (!HASNEXT) {   // layer-2 fp32 output, off the recurrence path
                float* hp = h3out + ((size_t)(b * 2000 + t)) * 512 + kwg * 8 + p * 2;
                hp[0] = hn0; hp[1] = hn1;
            }
        }
    }
}

__global__ __launch_bounds__(128, 1) void k_frame_lstm(
    const float* __restrict__ x,
    const float* __restrict__ Wih0, const float* __restrict__ Whh0, const float* __restrict__ b0,
    const float* __restrict__ Wih1, const float* __restrict__ Whh1, const float* __restrict__ b1,
    const float* __restrict__ Wih2, const float* __restrict__ Whh2, const float* __restrict__ b2,
    u16* hbuf, int* flags, float* h3out)
{
    __shared__ __align__(16) u16 sxpad[16 * 96];
    __shared__ float sC[32 * 17];
    const int wgid = blockIdx.x;
    const int layer = wgid >> 6;
    const int kwg = wgid & 63;
    if (layer == 0)      frame_body<3,  true,  true >(0, kwg, Wih0, Whh0, b0, x, hbuf, flags, h3out, sC, sxpad);
    else if (layer == 1) frame_body<16, false, true >(1, kwg, Wih1, Whh1, b1, x, hbuf, flags, h3out, sC, sxpad);
    else                 frame_body<16, false, false>(2, kwg, Wih2, Whh2, b2, x, hbuf, flags, h3out, sC, sxpad);
}

// ---------------------------------------------------------------------------
// Persistent word LSTM: 32 WGs x 128 threads, 100 steps, H=256. Round-0
// sync protocol; all-lane poll, direct per-lane A loads, 1 barrier/step.
// ---------------------------------------------------------------------------
__global__ __launch_bounds__(128, 1) void k_word_lstm(
    const u16* __restrict__ rW, const float* __restrict__ Wih,
    const float* __restrict__ Whh, const float* __restrict__ bias,
    u16* __restrict__ hbufw, int* __restrict__ flags, float* __restrict__ hseq)
{
    __shared__ float sC[32 * 17];
    const int tid = threadIdx.x;
    const int lane = tid & 63;
    const int wave = tid >> 6;
    const int n16 = lane & 15;
    const int quad = lane >> 4;
    const int koff = quad * 8;
    const int kwg = blockIdx.x;  // 0..31

    const int grow = wave * 512 + ((n16 >> 3) * 256) + kwg * 8 + (n16 & 7);
    short8 bfr[16];
#pragma unroll
    for (int kt = 0; kt < 8; ++kt) bfr[kt]     = ld8bf(Wih + (size_t)grow * 256 + kt * 32 + koff);
#pragma unroll
    for (int kt = 0; kt < 8; ++kt) bfr[8 + kt] = ld8bf(Whh + (size_t)grow * 256 + kt * 32 + koff);
    const int gb = tid & 15;
    const int gp4 = (tid >> 4) & 3;
    const int c0 = kwg * 8 + gp4 * 2;
    const float bI0 = bias[c0],       bI1 = bias[c0 + 1];
    const float bF0 = bias[256 + c0], bF1 = bias[256 + c0 + 1];
    const float bG0 = bias[512 + c0], bG1 = bias[512 + c0 + 1];
    const float bO0 = bias[768 + c0], bO1 = bias[768 + c0 + 1];
    float cp0 = 0.f, cp1 = 0.f;
    const int* fO = flags + 192 * FLAG_STRIDE;
    int* myflag   = flags + (192 + kwg) * FLAG_STRIDE;
    const int aoff = n16 * 256 + koff;
    __syncthreads();

    for (int t = 0; t < 100; ++t) {
        // all-lane poll (own layer only)
        {
            int guard = 0;
            for (;;) {
                const int fo = (lane < 32)
                    ? __hip_atomic_load(fO + lane * FLAG_STRIDE, __ATOMIC_RELAXED, __HIP_MEMORY_SCOPE_AGENT)
                    : BIGF;
                if (__all(fo >= t)) break;
                if (++guard > (1 << 22)) break;
                __builtin_amdgcn_s_sleep(1);
            }
        }

        const u16* hown = hbufw + ((size_t)((t + 7) & 7)) * 4096;
        short8 ha[8];
        if (t > 0) {
#pragma unroll
            for (int kt = 0; kt < 8; ++kt) ha[kt] = ldg16cv(hown + aoff + kt * 32);
        }
        f32x4 acc[4] = {{0,0,0,0},{0,0,0,0},{0,0,0,0},{0,0,0,0}};
#pragma unroll
        for (int kt = 0; kt < 8; ++kt) {
            short8 a = *(const short8*)(rW + ((size_t)(n16 * 100 + t)) * 256 + koff + kt * 32);
            acc[kt & 3] = mfma16(a, bfr[kt], acc[kt & 3]);
        }
        if (t > 0) {
            waitvm();
            __builtin_amdgcn_sched_barrier(0);
#pragma unroll
            for (int kt = 0; kt < 8; ++kt)
                acc[kt & 3] = mfma16(ha[kt], bfr[8 + kt], acc[kt & 3]);
        }
        const f32x4 C = acc[0] + acc[1] + acc[2] + acc[3];
#pragma unroll
        for (int r = 0; r < 4; ++r) sC[(wave * 16 + quad * 4 + r) * 17 + n16] = C[r];
        __syncthreads();

        if (tid < 64) {
            const int b = gb, p = gp4;
            float hn0, hn1;
            {
                const float gi = sC[b * 17 + p * 2]            + bI0;
                const float gf = sC[b * 17 + 8 + p * 2]        + bF0;
                const float gg = sC[(16 + b) * 17 + p * 2]     + bG0;
                const float go = sC[(16 + b) * 17 + 8 + p * 2] + bO0;
                const float cn = sigm(gf) * cp0 + sigm(gi) * tanhf(gg);
                hn0 = sigm(go) * tanhf(cn);
                cp0 = cn;
            }
            {
                const float gi = sC[b * 17 + p * 2 + 1]            + bI1;
                const float gf = sC[b * 17 + 8 + p * 2 + 1]        + bF1;
                const float gg = sC[(16 + b) * 17 + p * 2 + 1]     + bG1;
                const float go = sC[(16 + b) * 17 + 8 + p * 2 + 1] + bO1;
                const float cn = sigm(gf) * cp1 + sigm(gi) * tanhf(gg);
                hn1 = sigm(go) * tanhf(cn);
                cp1 = cn;
            }
            const u32 pk = ((u32)f2bf(hn0)) | (((u32)f2bf(hn1)) << 16);
            u32* hd = (u32*)(hbufw + ((size_t)(t & 7)) * 4096) + b * 128 + kwg * 4 + p;
            __hip_atomic_store(hd, pk, __ATOMIC_RELAXED, __HIP_MEMORY_SCOPE_AGENT);
            waitvm();
            if (tid == 0)
                __hip_atomic_store(myflag, t + 1, __ATOMIC_RELAXED, __HIP_MEMORY_SCOPE_AGENT);
            float* hp = hseq + ((size_t)(b * 100 + t)) * 256 + kwg * 8 + p * 2;
            hp[0] = hn0; hp[1] = hn1;
        }
    }
}

// ---------------------------------------------------------------------------
// Ragged tail-mean pooling from fp32 h3 (in d_out): reps fp32 (ws)
// ---------------------------------------------------------------------------
__global__ void k_pool(const float* __restrict__ h3, const int* __restrict__ x_lens,
                       const int* __restrict__ wstarts, const int* __restrict__ wends,
                       const int* __restrict__ wlens, const int* __restrict__ tailp,
                       float* __restrict__ reps)
{
    const int rw = blockIdx.x;
    const int b = rw / 100, w = rw - b * 100;
    const int tid = threadIdx.x;
    const int xl = x_lens[b];
    const int we = wends[rw];
    const int s0 = wstarts[rw];
    const int wl = wlens[b];
    const int tail = tailp[0];
    int ef = we < xl ? we : xl;
    int sf = s0 > 0 ? s0 : 0;
    int i0 = ef - tail; if (i0 < sf) i0 = sf;
    const bool valid = (w < wl) && (we > 0) && (ef > sf) && (ef > i0);
    float a0 = 0.f, a1 = 0.f;
    if (valid) {
        for (int t = i0; t < ef; ++t) {
            const float* hp = h3 + ((size_t)(b * 2000 + t)) * 512;
            a0 += hp[tid];
            a1 += hp[tid + 256];
        }
        const float inv = 1.f / (float)(ef - i0);
        a0 *= inv; a1 *= inv;
    }
    reps[(size_t)rw * 512 + tid] = a0;
    reps[(size_t)rw * 512 + tid + 256] = a1;
}

// ---------------------------------------------------------------------------
// In-place frame projection: y[b,t,:] = mask(h3[b,t,:]) @ fpW^T + fpb (fp32)
// ---------------------------------------------------------------------------
__global__ __launch_bounds__(256, 2) void k_frame_proj(
    float* __restrict__ y, const int* __restrict__ x_lens,
    const u16* __restrict__ fpWb, const float* __restrict__ fpb)
{
    __shared__ __align__(16) u16 As[16 * 520];
    const int tid = threadIdx.x, lane = tid & 63, wave = tid >> 6;
    const int n16 = lane & 15, quad = lane >> 4, koff = quad * 8;
    const int blk = blockIdx.x;          // 2000 blocks: 125 per batch
    const int b = blk / 125;
    const int t0 = (blk - b * 125) * 16;
    const int xl = x_lens[b];
    for (int c = tid; c < 2048; c += 256) {      // 16 rows x 128 float4
        const int row = c >> 7;
        const int q = c & 127;
        const int t = t0 + row;
        float4 v = {0.f, 0.f, 0.f, 0.f};
        if (t < xl) v = *(const float4*)(y + ((size_t)(b * 2000 + t)) * 512 + q * 4);
        u32* d = (u32*)(As + row * 520 + q * 4);
        d[0] = pk2(v.x, v.y);
        d[1] = pk2(v.z, v.w);
    }
    __syncthreads();
    const size_t rowbase = (size_t)b * 2000 + t0;
    for (int ct = 0; ct < 8; ++ct) {
        const int col0 = (wave * 8 + ct) * 16;
        f32x4 acc = {0, 0, 0, 0};
#pragma unroll
        for (int kt = 0; kt < 16; ++kt) {
            short8 a = *(const short8*)(As + n16 * 520 + kt * 32 + koff);
            short8 wv = *(const short8*)(fpWb + ((size_t)(col0 + n16)) * 512 + kt * 32 + koff);
            acc = mfma16(a, wv, acc);
        }
        const float bn = fpb[col0 + n16];
#pragma unroll
        for (int r = 0; r < 4; ++r) {
            const int m = quad * 4 + r;
            y[(rowbase + m) * 512 + col0 + n16] = acc[r] + bn;
        }
    }
}

// ---------------------------------------------------------------------------
// word_proj: Linear(512->256) + LayerNorm + exact GELU per (b,w) row.
// ---------------------------------------------------------------------------
__global__ void k_word_proj(const float* __restrict__ reps, const float* __restrict__ wpW,
                            const float* __restrict__ wpb, const float* __restrict__ lnW,
                            const float* __restrict__ lnB, u16* __restrict__ rW)
{
    __shared__ float sx[512];
    __shared__ float red[512];
    const int tid = threadIdx.x;
    const int row = blockIdx.x;
    for (int k = tid; k < 512; k += 256) sx[k] = reps[(size_t)row * 512 + k];
    __syncthreads();
    float acc = wpb[tid];
    const float4* wr = (const float4*)(wpW + (size_t)tid * 512);
    for (int k4 = 0; k4 < 128; ++k4) {
        const float4 w = wr[k4];
        acc += sx[k4 * 4] * w.x + sx[k4 * 4 + 1] * w.y + sx[k4 * 4 + 2] * w.z + sx[k4 * 4 + 3] * w.w;
    }
    red[tid] = acc; red[256 + tid] = acc * acc;
    __syncthreads();
    for (int s = 128; s > 0; s >>= 1) {
        if (tid < s) { red[tid] += red[tid + s]; red[256 + tid] += red[256 + tid + s]; }
        __syncthreads();
    }
    const float mu = red[0] * (1.f / 256.f);
    float var = red[256] * (1.f / 256.f) - mu * mu;
    if (var < 0.f) var = 0.f;
    const float xn = (acc - mu) * rsqrtf(var + 1e-5f);
    const float yv = xn * lnW[tid] + lnB[tid];
    const float g = 0.5f * yv * (1.0f + erff(yv * 0.70710678118654752f));
    rW[(size_t)row * 256 + tid] = f2bf(g);
}

// ---------------------------------------------------------------------------
// pred_sem = mask(hseq) @ spW^T + spb  (fp32 vector math)
// ---------------------------------------------------------------------------
__global__ void k_pred(const float* __restrict__ hseq, const int* __restrict__ wlens,
                       const float* __restrict__ spW, const float* __restrict__ spb,
                       float* __restrict__ out)
{
    __shared__ float sh[256];
    const int tid = threadIdx.x;
    const int rw = blockIdx.x;
    const int b = rw / 100, w = rw - b * 100;
    int wl = wlens[b]; if (wl < 1) wl = 1;
    const bool valid = (w < wl);
    sh[tid] = valid ? hseq[(size_t)rw * 256 + tid] : 0.f;
    __syncthreads();
    for (int o = tid; o < 512; o += 256) {
        float acc = spb[o];
        const float4* wr = (const float4*)(spW + (size_t)o * 256);
        for (int k4 = 0; k4 < 64; ++k4) {
            const float4 wv = wr[k4];
            acc += sh[k4 * 4] * wv.x + sh[k4 * 4 + 1] * wv.y + sh[k4 * 4 + 2] * wv.z + sh[k4 * 4 + 3] * wv.w;
        }
        out[PS_OFF + (size_t)rw * 512 + o] = acc;
    }
}

__global__ void k_xlens(const int* __restrict__ x_lens, float* __restrict__ out)
{
    const int tid = threadIdx.x;
    if (tid < 16) out[XL_OFF + tid] = (float)x_lens[tid];
}

// Pre-cast fpW (512x512 fp32) -> bf16
__global__ void k_cvt(const float* __restrict__ src, u16* __restrict__ dst)
{
    const int e = blockIdx.x * 256 + threadIdx.x;   // 65536 float4s
    const float4 v = *(const float4*)(src + (size_t)e * 4);
    u32* d = (u32*)(dst + (size_t)e * 4);
    d[0] = pk2(v.x, v.y);
    d[1] = pk2(v.z, v.w);
}

// Zero flags + frame h ring + word h ring: bytes [0, 491520) = 480x256 u32.
// No sentinels needed (L0/L2 edge conditions are compile-time).
__global__ void k_init(u32* __restrict__ p)
{
    p[blockIdx.x * 256 + threadIdx.x] = 0u;
}

// ---------------------------------------------------------------------------
extern "C" void kernel_launch(void* const* d_in, const int* in_sizes, int n_in,
                              void* d_out, int out_size, void* d_ws, size_t ws_size,
                              hipStream_t stream)
{
    (void)in_sizes; (void)n_in; (void)out_size; (void)ws_size;
    const float* x    = (const float*)d_in[0];
    const int* x_lens = (const int*)d_in[1];
    const int* wstart = (const int*)d_in[2];
    const int* wend   = (const int*)d_in[3];
    const int* wlen   = (const int*)d_in[4];
    const int* tailp  = (const int*)d_in[5];
    const float* Wih0 = (const float*)d_in[6];
    const float* Whh0 = (const float*)d_in[7];
    const float* b0   = (const float*)d_in[8];
    const float* Wih1 = (const float*)d_in[9];
    const float* Whh1 = (const float*)d_in[10];
    const float* b1   = (const float*)d_in[11];
    const float* Wih2 = (const float*)d_in[12];
    const float* Whh2 = (const float*)d_in[13];
    const float* b2   = (const float*)d_in[14];
    const float* fpW  = (const float*)d_in[15];
    const float* fpb  = (const float*)d_in[16];
    const float* wpW  = (const float*)d_in[17];
    const float* wpb  = (const float*)d_in[18];
    const float* lnW  = (const float*)d_in[19];
    const float* lnB  = (const float*)d_in[20];
    const float* wWih = (const float*)d_in[21];
    const float* wWhh = (const float*)d_in[22];
    const float* wb   = (const float*)d_in[23];
    const float* spW  = (const float*)d_in[24];
    const float* spb  = (const float*)d_in[25];

    float* out = (float*)d_out;
    char* ws = (char*)d_ws;
    int* flags  = (int*)(ws + WS_FLAGS);
    u16* hbufF  = (u16*)(ws + WS_HBUF_F);
    u16* hbufW  = (u16*)(ws + WS_HBUF_W);
    float* reps = (float*)(ws + WS_REPS);
    u16* rW     = (u16*)(ws + WS_RW);
    float* hseq = (float*)(ws + WS_HSEQ);
    u16* fpWb   = (u16*)(ws + WS_FPWB);

    k_init<<<480, 256, 0, stream>>>((u32*)d_ws);
    k_cvt<<<256, 256, 0, stream>>>(fpW, fpWb);
    k_frame_lstm<<<192, 128, 0, stream>>>(x, Wih0, Whh0, b0, Wih1, Whh1, b1,
                                          Wih2, Whh2, b2, hbufF, flags, out);
    k_pool<<<1600, 256, 0, stream>>>(out, x_lens, wstart, wend, wlen, tailp, reps);
    k_frame_proj<<<2000, 256, 0, stream>>>(out, x_lens, fpWb, fpb);  // after k_pool (in-place)
    k_word_proj<<<1600, 256, 0, stream>>>(reps, wpW, wpb, lnW, lnB, rW);
    k_word_lstm<<<32, 128, 0, stream>>>(rW, wWih, wWhh, wb, hbufW, flags, hseq);
    k_pred<<<1600, 256, 0, stream>>>(hseq, wlen, spW, spb, out);
    k_xlens<<<1, 64, 0, stream>>>(x_lens, out);
}